// Round 15
// baseline (192.955 us; speedup 1.0000x reference)
//
#include <hip/hip_runtime.h>
#include <hip/hip_bf16.h>
#include <math.h>

#define B_ 64
#define I_ 2048
#define K_ 16
#define N_ 32
#define D_ 32
#define SCH_ 16     // i-chunks for mfma sweep (128 i each)

typedef __attribute__((ext_vector_type(8))) short short8_t;   // 8 bf16
typedef __attribute__((ext_vector_type(4))) float f32x4_t;

// ws offsets (floats)
#define OFF_CT    0u           // cT    [N][I][B]        4194304
#define OFF_BT    4194304u     // bT    [N][I][B]        4194304
#define OFF_SPART 8388608u     // spart [N][SCH][B][D]   1048576
#define OFF_OT    9437184u     // oT    [N][B][D]          65536
#define OFF_XFRAG 9502720u     // xfrag [4][1024][64] uint4 = 1048576 f-slots
#define OFF_WBF   10551296u    // wbf   bf16 [N][I][D][K] = 16777216 f-slots (64 MiB)
// total 27328512 floats = 104.25 MiB (ws = 512 MiB per harness poison fills)

__device__ __forceinline__ unsigned int pk_bf16(float lo, float hi) {
    union { __hip_bfloat162 h2; unsigned int u; } cv;
    cv.h2 = __float22bfloat162_rn(float2{lo, hi});
    return cv.u;
}

// ---------------- W fp32 -> plain bf16 copy (pure streaming) ----------------
__global__ __launch_bounds__(256) void k_wconv(const float* __restrict__ W,
                                               uint4* __restrict__ wbf4) {
    const size_t tid = (size_t)blockIdx.x * 256 + threadIdx.x;  // one uint4 (8 bf16)
    const float4* W4 = (const float4*)W;
    const float4 a = W4[2 * tid];
    const float4 b = W4[2 * tid + 1];
    uint4 o;
    o.x = pk_bf16(a.x, a.y); o.y = pk_bf16(a.z, a.w);
    o.z = pk_bf16(b.x, b.y); o.w = pk_bf16(b.z, b.w);
    wbf4[tid] = o;
}

// ---------------- pack inputs into MFMA fragment order (bf16) ----------------
__global__ __launch_bounds__(256) void k_prep(const float* __restrict__ in,
                                              uint4* __restrict__ xfrag) {
    __shared__ float lds[B_][K_ + 1];
    const int i = blockIdx.x;
    const int t = threadIdx.x;
    const int b = t >> 2, kq = t & 3;
    const float4 v = *(const float4*)(in + ((size_t)b * I_ + i) * K_ + kq * 4);
    lds[b][kq * 4 + 0] = v.x; lds[b][kq * 4 + 1] = v.y;
    lds[b][kq * 4 + 2] = v.z; lds[b][kq * 4 + 3] = v.w;
    __syncthreads();
    if (t < 128) {
        const int m = t >> 5, r = t & 31, gl = r >> 4, kl = r & 15;
        const int bb = m * 16 + kl, k0 = 8 * gl;
        union { unsigned int u[4]; uint4 q; } o;
#pragma unroll
        for (int p = 0; p < 4; ++p)
            o.u[p] = pk_bf16(lds[bb][k0 + 2 * p], lds[bb][k0 + 2 * p + 1]);
        xfrag[((size_t)m * 1024 + (i >> 1)) * 64 + (2 * (i & 1) + gl) * 16 + kl] = o.q;
    }
}

// ---------------- MFMA s-sweep (B-frags straight from plain wbf) ----------------
template<int UNIFORM>
__global__ __launch_bounds__(512, 2) void k_sweep_mfma(const uint4* __restrict__ wbf4,
                                                       const uint4* __restrict__ xfrag,
                                                       const float* __restrict__ cT,
                                                       float* __restrict__ spart) {
    __shared__ float red[2][B_][D_ + 1];
    const int n = blockIdx.y, ch = blockIdx.x;
    const int t = threadIdx.x, w = t >> 6, l = t & 63;
    const int m = w >> 1, ks = w & 1;
    const int g = l >> 4;

    f32x4_t acc0 = {0.f, 0.f, 0.f, 0.f};
    f32x4_t acc1 = {0.f, 0.f, 0.f, 0.f};

    const uint4* xf = xfrag + (size_t)m * 65536 + l;            // + kk*64
    // B-frag lane address in plain wbf: i = 2kk+(g>>1), d=(l&15)+16nt, k0=8(g&1)
    // granule idx = (n*I + i)*64 + d*2 + (g&1)  (16B granules)
    const uint4* wb = wbf4 + (size_t)n * (I_ * 64)
                    + (size_t)(g >> 1) * 64 + (l & 15) * 2 + (g & 1);
    const int kk0 = ch * 64 + ks * 32;

    for (int tt = 0; tt < 32; ++tt) {
        const int kk = kk0 + tt;
        union { uint4 q; unsigned int u[4]; } xv;
        xv.q = xf[(size_t)kk * 64];
        union { unsigned int u[4]; short8_t v; } af;
        if (UNIFORM) {
            af.u[0] = xv.u[0]; af.u[1] = xv.u[1];
            af.u[2] = xv.u[2]; af.u[3] = xv.u[3];
        } else {
            const float c = cT[((size_t)n * I_ + 2 * kk + (l >> 5)) * B_
                               + m * 16 + (l & 15)];
#pragma unroll
            for (int p = 0; p < 4; ++p) {
                const unsigned int uu = xv.u[p];
                const float lo = __uint_as_float(uu << 16);
                const float hi = __uint_as_float(uu & 0xffff0000u);
                af.u[p] = pk_bf16(lo * c, hi * c);
            }
        }
        union { uint4 q; short8_t v; } b0, b1;
        b0.q = wb[(size_t)kk * 128];          // nt=0 (d 0..15)
        b1.q = wb[(size_t)kk * 128 + 32];     // nt=1 (d 16..31)

        acc0 = __builtin_amdgcn_mfma_f32_16x16x32_bf16(af.v, b0.v, acc0, 0, 0, 0);
        acc1 = __builtin_amdgcn_mfma_f32_16x16x32_bf16(af.v, b1.v, acc1, 0, 0, 0);
    }

#pragma unroll
    for (int r = 0; r < 4; ++r) {
        const int row = m * 16 + (l >> 4) * 4 + r;
        red[ks][row][(l & 15)]      = acc0[r];
        red[ks][row][16 + (l & 15)] = acc1[r];
    }
    __syncthreads();
#pragma unroll
    for (int q = 0; q < 4; ++q) {
        const int j = q * 512 + t;                  // j = b*32 + d
        const int b = j >> 5, d = j & 31;
        spart[((size_t)n * SCH_ + ch) * (B_ * D_) + j] = red[0][b][d] + red[1][b][d];
    }
}

// ---------------- reduce + squash -> oT [N][B][D] (or final out) ----------------
template<int FINAL>
__global__ __launch_bounds__(256) void k_reduce(const float* __restrict__ spart,
                                                float* __restrict__ oT,
                                                float* __restrict__ out,
                                                float prescale) {
    const int gt = blockIdx.x * 256 + threadIdx.x;   // = n*2048 + b*32 + d
    const int n = gt >> 11;
    const int rem = gt & 2047;
    const int b = rem >> 5, d = rem & 31;
    const float* sp = spart + (size_t)n * (SCH_ * B_ * D_) + rem;
    float s = 0.f;
#pragma unroll
    for (int p = 0; p < SCH_; ++p) s += sp[p * (B_ * D_)];
    s *= prescale;

    float sq = s * s;
#pragma unroll
    for (int off = 16; off >= 1; off >>= 1) sq += __shfl_xor(sq, off, 64);
    const float scale = sq / ((1.0f + sq) * sqrtf(sq + 1e-7f));
    const float o = scale * s;
    if (FINAL) {
        out[((size_t)b * N_ + n) * D_ + d] = o;       // [B][N][D]
    } else {
        oT[gt] = o;                                   // [N][B][D], coalesced
    }
}

// ---------------- fused b-update + softmax (plain-wbf A, xfrag B, fp32 o) -------
// Wave = (btile, i-pair). Per n: 2 h-halves x {A-load (zero-masked parity),
// 2 MFMA, oT float4, dot}. Epilogue shfl over g-groups; softmax both i's.
template<int FIRST>
__global__ __launch_bounds__(512, 2) void k_updsm(const uint4* __restrict__ wbf4,
                                                  const uint4* __restrict__ xfrag,
                                                  const float* __restrict__ oT,
                                                  float* __restrict__ bT,
                                                  float* __restrict__ cT) {
    const int t = threadIdx.x, w = t >> 6, l = t & 63;
    const int btile = w & 3;
    const int p = blockIdx.x * 2 + (w >> 2);      // i-pair
    const int i_e = 2 * p;
    const int g = l >> 4, kl = l & 15;
    const int bp = btile * 16 + kl;               // b'

    union { uint4 q; short8_t v; } xf;            // B-frag (n-independent)
    xf.q = xfrag[((size_t)btile * 1024 + p) * 64 + l];

    const int i_l = i_e + (g >> 1);               // lanes g<2 -> i_e, g>=2 -> i_o
    const uint4* wrow = wbf4 + (size_t)i_l * 64 + kl * 2 + (g & 1);
    const uint4 z4 = {0u, 0u, 0u, 0u};

    float bne[N_], bno[N_];
#pragma unroll
    for (int n = 0; n < N_; ++n) {
        const uint4* wb = wrow + (size_t)n * (I_ * 64);
        const float* op = oT + (size_t)n * 2048 + bp * 32 + 4 * g;
        float ge = 0.f, go = 0.f;
#pragma unroll
        for (int h = 0; h < 2; ++h) {
            union { uint4 q; short8_t v; } av, ae, ao;
            av.q = wb[32 * h];
            ae.q = (g < 2) ? av.q : z4;
            ao.q = (g < 2) ? z4 : av.q;
            f32x4_t ce = {0.f, 0.f, 0.f, 0.f};
            f32x4_t co = {0.f, 0.f, 0.f, 0.f};
            ce = __builtin_amdgcn_mfma_f32_16x16x32_bf16(ae.v, xf.v, ce, 0, 0, 0);
            co = __builtin_amdgcn_mfma_f32_16x16x32_bf16(ao.v, xf.v, co, 0, 0, 0);
            const float4 o4 = *(const float4*)(op + 16 * h);
            ge += ce[0] * o4.x + ce[1] * o4.y + ce[2] * o4.z + ce[3] * o4.w;
            go += co[0] * o4.x + co[1] * o4.y + co[2] * o4.z + co[3] * o4.w;
        }
        ge += __shfl_xor(ge, 16, 64);  ge += __shfl_xor(ge, 32, 64);
        go += __shfl_xor(go, 16, 64);  go += __shfl_xor(go, 32, 64);
        const size_t be = ((size_t)n * I_ + i_e) * B_ + bp;
        if (FIRST) {
            if (l < 16) { bT[be] = ge; bT[be + B_] = go; }
        } else {
            ge += bT[be];
            go += bT[be + B_];
        }
        bne[n] = ge;  bno[n] = go;
    }

    // softmax over n for both i's
    float me = bne[0], mo = bno[0];
#pragma unroll
    for (int n = 1; n < N_; ++n) { me = fmaxf(me, bne[n]); mo = fmaxf(mo, bno[n]); }
    float se = 0.f, so = 0.f;
#pragma unroll
    for (int n = 0; n < N_; ++n) {
        bne[n] = __expf(bne[n] - me); se += bne[n];
        bno[n] = __expf(bno[n] - mo); so += bno[n];
    }
    const float ie = 1.0f / se, io = 1.0f / so;
    if (l < 16) {
#pragma unroll
        for (int n = 0; n < N_; ++n) {
            const size_t ce = ((size_t)n * I_ + i_e) * B_ + bp;
            cT[ce]      = bne[n] * ie;
            cT[ce + B_] = bno[n] * io;
        }
    }
}

extern "C" void kernel_launch(void* const* d_in, const int* in_sizes, int n_in,
                              void* d_out, int out_size, void* d_ws, size_t ws_size,
                              hipStream_t stream) {
    const float* inputs = (const float*)d_in[0];
    const float* W      = (const float*)d_in[1];
    float* out = (float*)d_out;
    float* ws  = (float*)d_ws;
    float* cT    = ws + OFF_CT;
    float* bT    = ws + OFF_BT;
    float* spart = ws + OFF_SPART;
    float* oT    = ws + OFF_OT;
    uint4* xfrag = (uint4*)(ws + OFF_XFRAG);
    uint4* wbf4  = (uint4*)(ws + OFF_WBF);

    k_wconv<<<(N_ * I_ * D_ * K_) / (8 * 256), 256, 0, stream>>>(W, wbf4);
    k_prep<<<I_, 256, 0, stream>>>(inputs, xfrag);
    // r = 0 (uniform c = 1/N as prescale)
    k_sweep_mfma<1><<<dim3(SCH_, N_), 512, 0, stream>>>(wbf4, xfrag, cT, spart);
    k_reduce<0><<<256, 256, 0, stream>>>(spart, oT, out, 1.0f / N_);
    k_updsm<1><<<I_ / 4, 512, 0, stream>>>(wbf4, xfrag, oT, bT, cT);
    // r = 1
    k_sweep_mfma<0><<<dim3(SCH_, N_), 512, 0, stream>>>(wbf4, xfrag, cT, spart);
    k_reduce<0><<<256, 256, 0, stream>>>(spart, oT, out, 1.0f);
    k_updsm<0><<<I_ / 4, 512, 0, stream>>>(wbf4, xfrag, oT, bT, cT);
    // r = 2
    k_sweep_mfma<0><<<dim3(SCH_, N_), 512, 0, stream>>>(wbf4, xfrag, cT, spart);
    k_reduce<1><<<256, 256, 0, stream>>>(spart, oT, out, 1.0f);
}